// Round 13
// baseline (607.966 us; speedup 1.0000x reference)
//
#include <hip/hip_runtime.h>
#include <hip/hip_bf16.h>
#include <math.h>

#define EPSF 1e-5f
#define LOG2E 1.4426950408889634f
#define LN2 0.6931471805599453f

typedef __attribute__((ext_vector_type(4))) float f32x4;
typedef __attribute__((ext_vector_type(8))) short s16x8;

__device__ __forceinline__ float hw_exp2(float x) { return __builtin_amdgcn_exp2f(x); }
__device__ __forceinline__ float hw_log2(float x) { return __builtin_amdgcn_logf(x); }
__device__ __forceinline__ float fast_rcp(float x) { return __builtin_amdgcn_rcpf(x); }

// ---------- block reduction (256 threads = 4 waves) ----------
__device__ __forceinline__ float block_reduce_sum_256(float s) {
  #pragma unroll
  for (int o = 32; o > 0; o >>= 1) s += __shfl_xor(s, o, 64);
  __shared__ float red[4];
  int lane = threadIdx.x & 63, wid = threadIdx.x >> 6;
  if (lane == 0) red[wid] = s;
  __syncthreads();
  return red[0] + red[1] + red[2] + red[3];
}

__device__ __forceinline__ unsigned short f2bu(float f) {
  __hip_bfloat16 b = __float2bfloat16(f);
  return __builtin_bit_cast(unsigned short, b);
}

// ---------- K0: h = expmap0(x) as bf16; cx2, 1/(1-cx2) per row (float4) ----------
__global__ void k_expmap(const float* __restrict__ x, __hip_bfloat16* __restrict__ h,
                         float* __restrict__ cx2, float* __restrict__ invomc, int K) {
  int row = blockIdx.x, t = threadIdx.x;
  const float4* xr = (const float4*)(x + (size_t)row * K);
  float4 v[4];
  float s = 0.f;
  #pragma unroll
  for (int i = 0; i < 4; ++i) {
    v[i] = xr[t + (i << 8)];
    s += v[i].x * v[i].x + v[i].y * v[i].y + v[i].z * v[i].z + v[i].w * v[i].w;
  }
  float nsq = block_reduce_sum_256(s);
  float n = fmaxf(sqrtf(nsq), EPSF);
  float e2 = hw_exp2(2.f * LOG2E * n);
  float th = 1.f - 2.f * fast_rcp(e2 + 1.f);
  float sc = th * fast_rcp(n);        // tanh(n)/n, rc = 1
  float hn2 = sc * sc * nsq;          // ||h||^2
  float c2 = fminf(hn2, 1.f - EPSF);
  if (t == 0) { cx2[row] = c2; invomc[row] = 1.f / (1.f - c2); }
  ushort4* hr = (ushort4*)(h + (size_t)row * K);
  #pragma unroll
  for (int i = 0; i < 4; ++i) {
    ushort4 o;
    o.x = f2bu(sc * v[i].x); o.y = f2bu(sc * v[i].y);
    o.z = f2bu(sc * v[i].z); o.w = f2bu(sc * v[i].w);
    hr[t + (i << 8)] = o;
  }
}

// ---------- K1a: partial column sum-of-squares of z (float4, deterministic) ----------
__global__ void k_colsq(const float* __restrict__ z, float* __restrict__ part,
                        int K, int N, int rows_per_chunk) {
  int c4 = blockIdx.x * 256 + threadIdx.x;    // float4 column index
  int r0 = blockIdx.y * rows_per_chunk;
  const float4* z4 = (const float4*)z;
  int n4 = N >> 2;
  float4 a = {0.f, 0.f, 0.f, 0.f};
  for (int r = r0; r < r0 + rows_per_chunk; ++r) {
    float4 v = z4[(size_t)r * n4 + c4];
    a.x += v.x * v.x; a.y += v.y * v.y; a.z += v.z * v.z; a.w += v.w * v.w;
  }
  ((float4*)part)[(size_t)blockIdx.y * n4 + c4] = a;
}

// ---------- K1b: finalize per-column scalars ----------
__global__ void k_colfin(const float* __restrict__ part, const float* __restrict__ bias,
                         float* __restrict__ zn2, float* __restrict__ invzn,
                         float* __restrict__ ch, float* __restrict__ sh,
                         int N, int nchunk) {
  int c = blockIdx.x * 256 + threadIdx.x;
  float s = 0.f;
  for (int i = 0; i < nchunk; ++i) s += part[(size_t)i * N + c];
  float zn = fmaxf(sqrtf(s), EPSF);
  zn2[c] = 2.f * zn;
  invzn[c] = 1.f / zn;
  float d = 2.f * bias[c];
  float ep = hw_exp2(LOG2E * d);
  float em = fast_rcp(ep);
  ch[c] = 0.5f * (ep + em);
  sh[c] = 0.5f * (ep - em);
}

// ---------- K1c: z_unit^T (N x K) bf16, LDS tile transpose ----------
__global__ void k_zunitT(const float* __restrict__ z, const float* __restrict__ invzn,
                         __hip_bfloat16* __restrict__ zt, int K, int N) {
  __shared__ float tile[32][33];
  int tx = threadIdx.x, ty = threadIdx.y;   // (32,8)
  int c0 = blockIdx.x * 32, r0 = blockIdx.y * 32;
  float inv = invzn[c0 + tx];
  #pragma unroll
  for (int i = 0; i < 4; ++i)
    tile[ty + i * 8][tx] = z[(size_t)(r0 + ty + i * 8) * N + c0 + tx] * inv;
  __syncthreads();
  #pragma unroll
  for (int i = 0; i < 4; ++i)
    zt[(size_t)(c0 + ty + i * 8) * K + r0 + tx] = __float2bfloat16(tile[tx][ty + i * 8]);
}

// force a (uniform) pointer into SGPRs so global_load_lds uses saddr form
__device__ __forceinline__ const char* RFL64(const char* p) {
  unsigned long long b = (unsigned long long)p;
  unsigned int lo = __builtin_amdgcn_readfirstlane((unsigned int)b);
  unsigned int hi = __builtin_amdgcn_readfirstlane((unsigned int)(b >> 32));
  return (const char*)(((unsigned long long)hi << 32) | lo);
}

// ---------- K2: 256x256 bf16 MFMA GEMM, software-pipelined fragments ----------
// 2 phases/K-tile, 1 barrier/K-tile, counted lgkmcnt so LDS delivery overlaps
// MFMA execution:
//   A: read b(8)+a1(8) [buf D]; lgkmcnt(8) (b done, a1 in flight);
//      32 MFMA (a0 x b0..b3); lgkmcnt(0); vmcnt(0); barrier
//   B: stage kt+2 -> buf D (8 loads); read a0'(8) [buf D^1, next tile];
//      32 MFMA (a1 x b0..b3)   [a1 reads completed during MFMA_A]
// a0'/next-tile reads complete during MFMA_B; consumed after next A's
// lgkmcnt(8). vmcnt(0) at A-end drains only stages issued >=1 full tile ago.
// WAR: stage into buf D at B(kt) is preceded by lgkmcnt(0)+barrier at A(kt),
// which covers every read of buf D (RD_A0 at B(kt-1), RD_B/RD_A1 at A(kt)).
__global__ __launch_bounds__(512, 2) void k_gemm_dot(
    const __hip_bfloat16* __restrict__ A,   // h: M x K
    const __hip_bfloat16* __restrict__ Bt,  // z_unit^T: N x K
    float* __restrict__ dot, int M, int N, int K) {
  __shared__ __align__(16) char smem[131072];
  const int K2 = K * 2;
  int tid = threadIdx.x, lane = tid & 63, wid = tid >> 6;
  int wm = wid >> 2, wn = wid & 3;

  // bijective XCD swizzle (gridDim.x % 8 == 0 here: 512 blocks)
  int bid = blockIdx.x;
  int cpx = gridDim.x >> 3;
  int swz = (bid & 7) * cpx + (bid >> 3);
  int nbx = N >> 8;
  int bx = swz % nbx, by = swz / nbx;
  int bm0 = by * 256, bn0 = bx * 256;

  // ---- staging: per-lane 32-bit offsets (inverse-swizzled source) ----
  int rr = (tid >> 2) & 15;
  int cbyte = ((tid & 3) * 16) ^ ((rr & 8) << 2);
  int kb = ((tid >> 6) & 1) * 64 + cbyte;          // k-byte within tile [0,128)
  int r0 = ((tid >> 7) << 4) + rr;                 // row (j=0); j=1 adds 64
  unsigned int off0 = (unsigned int)(r0 * K2 + kb);
  unsigned int off1 = off0 + (unsigned int)(64 * K2);
  int ldsW = wid * 1024;                           // linear dest (lane*16 implicit)

  const char* aPan0 = (const char*)A + (size_t)bm0 * K2;
  const char* aPan1 = aPan0 + (size_t)128 * K2;
  const char* bPan0 = (const char*)Bt + (size_t)bn0 * K2;
  const char* bPan1 = bPan0 + (size_t)128 * K2;

  auto STAGE = [&](const char* base, int ldsBase) {
    __builtin_amdgcn_global_load_lds(
        (const __attribute__((address_space(1))) unsigned int*)(base + off0),
        (__attribute__((address_space(3))) unsigned int*)(smem + ldsBase + ldsW), 16, 0, 0);
    __builtin_amdgcn_global_load_lds(
        (const __attribute__((address_space(1))) unsigned int*)(base + off1),
        (__attribute__((address_space(3))) unsigned int*)(smem + ldsBase + ldsW + 8192), 16, 0, 0);
  };

  // ---- LDS read bases (swizzled) ----
  int labase = (lane & 15) * 64 + (((lane >> 4) * 16) ^ ((lane & 8) << 2));
  const char* pA0 = smem + wm * 16384 + labase;
  const char* pA1 = pA0 + 65536;
  const char* pB0 = smem + 32768 + (wn >> 1) * 16384 + (wn & 1) * 8192 + labase;
  const char* pB1 = pB0 + 65536;

  s16x8 a0f[2][4][2], a1f[2][4][2], bvf[2][4][2];
  f32x4 acc[8][4] = {};

#define RD_A0(D) do { const char* p_ = ((D) ? pA1 : pA0); \
    _Pragma("unroll") for (int i_ = 0; i_ < 4; ++i_) { \
      a0f[D][i_][0] = *(const s16x8*)(p_ + i_ * 2048); \
      a0f[D][i_][1] = *(const s16x8*)(p_ + i_ * 2048 + 1024); } } while (0)
#define RD_A1(D) do { const char* p_ = ((D) ? pA1 : pA0); \
    _Pragma("unroll") for (int i_ = 0; i_ < 4; ++i_) { \
      a1f[D][i_][0] = *(const s16x8*)(p_ + 8192 + i_ * 2048); \
      a1f[D][i_][1] = *(const s16x8*)(p_ + 8192 + i_ * 2048 + 1024); } } while (0)
#define RD_B(D) do { const char* p_ = ((D) ? pB1 : pB0); \
    _Pragma("unroll") for (int f_ = 0; f_ < 4; ++f_) { \
      bvf[D][f_][0] = *(const s16x8*)(p_ + f_ * 2048); \
      bvf[D][f_][1] = *(const s16x8*)(p_ + f_ * 2048 + 1024); } } while (0)
#define MM_A(D) do { \
    _Pragma("unroll") for (int i_ = 0; i_ < 4; ++i_) \
      _Pragma("unroll") for (int f_ = 0; f_ < 4; ++f_) { \
        acc[i_][f_] = __builtin_amdgcn_mfma_f32_16x16x32_bf16( \
            bvf[D][f_][0], a0f[D][i_][0], acc[i_][f_], 0, 0, 0); \
        acc[i_][f_] = __builtin_amdgcn_mfma_f32_16x16x32_bf16( \
            bvf[D][f_][1], a0f[D][i_][1], acc[i_][f_], 0, 0, 0); } } while (0)
#define MM_B(D) do { \
    _Pragma("unroll") for (int i_ = 0; i_ < 4; ++i_) \
      _Pragma("unroll") for (int f_ = 0; f_ < 4; ++f_) { \
        acc[4 + i_][f_] = __builtin_amdgcn_mfma_f32_16x16x32_bf16( \
            bvf[D][f_][0], a1f[D][i_][0], acc[4 + i_][f_], 0, 0, 0); \
        acc[4 + i_][f_] = __builtin_amdgcn_mfma_f32_16x16x32_bf16( \
            bvf[D][f_][1], a1f[D][i_][1], acc[4 + i_][f_], 0, 0, 0); } } while (0)

  int NT = K >> 6;   // K-tiles of 64 (assumed even)

  // ---- prologue: stage tile0 + tile1; pre-read a0 of tile0 ----
  {
    const char* a0 = RFL64(aPan0); const char* a1 = RFL64(aPan1);
    const char* b0 = RFL64(bPan0); const char* b1 = RFL64(bPan1);
    STAGE(b0, 32768); STAGE(b1, 49152); STAGE(a0, 0); STAGE(a1, 16384);
  }
  if (NT > 1) {
    const char* a0 = RFL64(aPan0 + 128); const char* a1 = RFL64(aPan1 + 128);
    const char* b0 = RFL64(bPan0 + 128); const char* b1 = RFL64(bPan1 + 128);
    STAGE(b0, 65536 + 32768); STAGE(b1, 65536 + 49152);
    STAGE(a0, 65536); STAGE(a1, 65536 + 16384);
    asm volatile("s_waitcnt vmcnt(8)");
  } else {
    asm volatile("s_waitcnt vmcnt(0)");
  }
  __builtin_amdgcn_s_barrier();
  RD_A0(0);

#define KTILE(D, KT) do { \
    bool st_ = ((KT) + 2 < NT); \
    bool nx_ = ((KT) + 1 < NT); \
    int kOff2_ = ((KT) + 2) << 7; \
    const char* aB0_ = RFL64(aPan0 + kOff2_); \
    const char* aB1_ = RFL64(aPan1 + kOff2_); \
    const char* bB0_ = RFL64(bPan0 + kOff2_); \
    const char* bB1_ = RFL64(bPan1 + kOff2_); \
    /* phase A */ \
    RD_B(D); RD_A1(D); \
    asm volatile("s_waitcnt lgkmcnt(8)"); \
    __builtin_amdgcn_s_setprio(1); MM_A(D); __builtin_amdgcn_s_setprio(0); \
    asm volatile("s_waitcnt lgkmcnt(0)"); \
    asm volatile("s_waitcnt vmcnt(0)"); \
    __builtin_amdgcn_s_barrier(); \
    /* phase B */ \
    if (st_) { STAGE(bB0_, (D) * 65536 + 32768); STAGE(bB1_, (D) * 65536 + 49152); \
               STAGE(aB0_, (D) * 65536); STAGE(aB1_, (D) * 65536 + 16384); } \
    if (nx_) { RD_A0((D) ^ 1); } \
    __builtin_amdgcn_s_setprio(1); MM_B(D); __builtin_amdgcn_s_setprio(0); \
  } while (0)

  for (int kt = 0; kt < NT; kt += 2) {
    KTILE(0, kt);
    KTILE(1, kt + 1);
  }
#undef KTILE
#undef RD_A0
#undef RD_A1
#undef RD_B
#undef MM_A
#undef MM_B

  // ---- epilogue: float4 stores (transposed fragment layout) ----
  int ml = lane & 15, ng = lane >> 4;
  #pragma unroll
  for (int fm = 0; fm < 8; ++fm) {
    int row = bm0 + wm * 128 + fm * 16 + ml;
    size_t rowo = (size_t)row * N + bn0 + wn * 64 + ng * 4;
    #pragma unroll
    for (int fn = 0; fn < 4; ++fn) {
      *(f32x4*)(dot + rowo + fn * 16) = acc[fm][fn];
    }
  }
}

// ---------- K3: MLR + ball-lift + logmap0, hw-transcendental, in place ----------
// y = sinh(s*asinh(u)) = 0.5*(w^s - w^(-s)), w = u + sqrt(u^2+1), s = zn2[c].
__global__ void k_mlr_final(float* __restrict__ io, const float* __restrict__ cx2,
                            const float* __restrict__ invomc, const float* __restrict__ zn2,
                            const float* __restrict__ chb, const float* __restrict__ shb,
                            int N) {
  int row = blockIdx.x, t = threadIdx.x;
  float4* ior = (float4*)(io + (size_t)row * N);
  const float4* ch4 = (const float4*)chb;
  const float4* sh4 = (const float4*)shb;
  const float4* z24 = (const float4*)zn2;
  float c2 = cx2[row], inv = invomc[row];
  float opc = 1.f + c2;
  float y[4][4];
  float s = 0.f;
  #pragma unroll
  for (int i = 0; i < 4; ++i) {
    int idx = t + (i << 8);
    float4 d = ior[idx], ch = ch4[idx], sh = sh4[idx], z2 = z24[idx];
    float dq[4] = {d.x, d.y, d.z, d.w};
    float chq[4] = {ch.x, ch.y, ch.z, ch.w};
    float shq[4] = {sh.x, sh.y, sh.z, sh.w};
    float zq[4] = {z2.x, z2.y, z2.z, z2.w};
    #pragma unroll
    for (int q = 0; q < 4; ++q) {
      float u = (2.f * dq[q] * chq[q] - opc * shq[q]) * inv;
      float w = u + sqrtf(fmaf(u, u, 1.f));
      float p = hw_log2(w);
      float tq = zq[q] * p;
      float ep = hw_exp2(tq);
      float em = hw_exp2(-tq);
      float yy = 0.5f * (ep - em);
      y[i][q] = yy;
      s += yy * yy;
    }
  }
  float ny2 = block_reduce_sum_256(s);
  float ny = sqrtf(ny2);
  float sfac = fast_rcp(1.f + sqrtf(1.f + ny2));  // lift: y_ball = sfac*y
  float w = sfac * ny;
  float nw = fmaxf(w, EPSF);
  float tt = fminf(nw, 1.f - EPSF);
  float la = 0.5f * LN2 * hw_log2((1.f + tt) * fast_rcp(1.f - tt));
  float coef = la * sfac * fast_rcp(nw);
  #pragma unroll
  for (int i = 0; i < 4; ++i) {
    int idx = t + (i << 8);
    float4 o;
    o.x = coef * y[i][0]; o.y = coef * y[i][1];
    o.z = coef * y[i][2]; o.w = coef * y[i][3];
    ior[idx] = o;
  }
}

extern "C" void kernel_launch(void* const* d_in, const int* in_sizes, int n_in,
                              void* d_out, int out_size, void* d_ws, size_t ws_size,
                              hipStream_t stream) {
  const float* x    = (const float*)d_in[0];
  const float* z    = (const float*)d_in[1];
  const float* bias = (const float*)d_in[2];
  float* out = (float*)d_out;

  int N = in_sizes[2];           // DOUT = 4096
  int K = in_sizes[1] / N;       // DIN  = 4096
  int M = in_sizes[0] / K;       // B    = 8192

  char* ws = (char*)d_ws;
  size_t o = 0;
  __hip_bfloat16* h  = (__hip_bfloat16*)(ws + o); o += (size_t)M * K * 2;
  __hip_bfloat16* zt = (__hip_bfloat16*)(ws + o); o += (size_t)N * K * 2;
  float* cx2    = (float*)(ws + o); o += (size_t)M * 4;
  float* invomc = (float*)(ws + o); o += (size_t)M * 4;
  float* part   = (float*)(ws + o); o += (size_t)32 * N * 4;
  float* zn2    = (float*)(ws + o); o += (size_t)N * 4;
  float* invzn  = (float*)(ws + o); o += (size_t)N * 4;
  float* chb    = (float*)(ws + o); o += (size_t)N * 4;
  float* shb    = (float*)(ws + o); o += (size_t)N * 4;

  const int NCH = 32;
  k_expmap<<<M, 256, 0, stream>>>(x, h, cx2, invomc, K);
  k_colsq<<<dim3(N / 1024, NCH), 256, 0, stream>>>(z, part, K, N, K / NCH);
  k_colfin<<<N / 256, 256, 0, stream>>>(part, bias, zn2, invzn, chb, shb, N, NCH);
  k_zunitT<<<dim3(N / 32, K / 32), dim3(32, 8), 0, stream>>>(z, invzn, zt, K, N);
  int grid = (M / 256) * (N / 256);
  k_gemm_dot<<<grid, 512, 0, stream>>>(h, zt, out, M, N, K);
  k_mlr_final<<<M, 256, 0, stream>>>(out, cx2, invomc, zn2, chb, shb, N);
}

// Round 14
// 473.945 us; speedup vs baseline: 1.2828x; 1.2828x over previous
//
#include <hip/hip_runtime.h>
#include <hip/hip_bf16.h>
#include <math.h>

#define EPSF 1e-5f
#define LOG2E 1.4426950408889634f
#define LN2 0.6931471805599453f

typedef __attribute__((ext_vector_type(4))) float f32x4;
typedef __attribute__((ext_vector_type(8))) short s16x8;

__device__ __forceinline__ float hw_exp2(float x) { return __builtin_amdgcn_exp2f(x); }
__device__ __forceinline__ float hw_log2(float x) { return __builtin_amdgcn_logf(x); }
__device__ __forceinline__ float fast_rcp(float x) { return __builtin_amdgcn_rcpf(x); }

// ---------- block reduction (256 threads = 4 waves) ----------
__device__ __forceinline__ float block_reduce_sum_256(float s) {
  #pragma unroll
  for (int o = 32; o > 0; o >>= 1) s += __shfl_xor(s, o, 64);
  __shared__ float red[4];
  int lane = threadIdx.x & 63, wid = threadIdx.x >> 6;
  if (lane == 0) red[wid] = s;
  __syncthreads();
  return red[0] + red[1] + red[2] + red[3];
}

__device__ __forceinline__ unsigned short f2bu(float f) {
  __hip_bfloat16 b = __float2bfloat16(f);
  return __builtin_bit_cast(unsigned short, b);
}

// ---------- K0: h = expmap0(x) as bf16; cx2, 1/(1-cx2) per row (float4) ----------
__global__ void k_expmap(const float* __restrict__ x, __hip_bfloat16* __restrict__ h,
                         float* __restrict__ cx2, float* __restrict__ invomc, int K) {
  int row = blockIdx.x, t = threadIdx.x;
  const float4* xr = (const float4*)(x + (size_t)row * K);
  float4 v[4];
  float s = 0.f;
  #pragma unroll
  for (int i = 0; i < 4; ++i) {
    v[i] = xr[t + (i << 8)];
    s += v[i].x * v[i].x + v[i].y * v[i].y + v[i].z * v[i].z + v[i].w * v[i].w;
  }
  float nsq = block_reduce_sum_256(s);
  float n = fmaxf(sqrtf(nsq), EPSF);
  float e2 = hw_exp2(2.f * LOG2E * n);
  float th = 1.f - 2.f * fast_rcp(e2 + 1.f);
  float sc = th * fast_rcp(n);        // tanh(n)/n, rc = 1
  float hn2 = sc * sc * nsq;          // ||h||^2
  float c2 = fminf(hn2, 1.f - EPSF);
  if (t == 0) { cx2[row] = c2; invomc[row] = 1.f / (1.f - c2); }
  ushort4* hr = (ushort4*)(h + (size_t)row * K);
  #pragma unroll
  for (int i = 0; i < 4; ++i) {
    ushort4 o;
    o.x = f2bu(sc * v[i].x); o.y = f2bu(sc * v[i].y);
    o.z = f2bu(sc * v[i].z); o.w = f2bu(sc * v[i].w);
    hr[t + (i << 8)] = o;
  }
}

// ---------- K1a: partial column sum-of-squares of z (float4, deterministic) ----------
__global__ void k_colsq(const float* __restrict__ z, float* __restrict__ part,
                        int K, int N, int rows_per_chunk) {
  int c4 = blockIdx.x * 256 + threadIdx.x;    // float4 column index
  int r0 = blockIdx.y * rows_per_chunk;
  const float4* z4 = (const float4*)z;
  int n4 = N >> 2;
  float4 a = {0.f, 0.f, 0.f, 0.f};
  for (int r = r0; r < r0 + rows_per_chunk; ++r) {
    float4 v = z4[(size_t)r * n4 + c4];
    a.x += v.x * v.x; a.y += v.y * v.y; a.z += v.z * v.z; a.w += v.w * v.w;
  }
  ((float4*)part)[(size_t)blockIdx.y * n4 + c4] = a;
}

// ---------- K1b: finalize per-column scalars ----------
__global__ void k_colfin(const float* __restrict__ part, const float* __restrict__ bias,
                         float* __restrict__ zn2, float* __restrict__ invzn,
                         float* __restrict__ ch, float* __restrict__ sh,
                         int N, int nchunk) {
  int c = blockIdx.x * 256 + threadIdx.x;
  float s = 0.f;
  for (int i = 0; i < nchunk; ++i) s += part[(size_t)i * N + c];
  float zn = fmaxf(sqrtf(s), EPSF);
  zn2[c] = 2.f * zn;
  invzn[c] = 1.f / zn;
  float d = 2.f * bias[c];
  float ep = hw_exp2(LOG2E * d);
  float em = fast_rcp(ep);
  ch[c] = 0.5f * (ep + em);
  sh[c] = 0.5f * (ep - em);
}

// ---------- K1c: z_unit^T (N x K) bf16, LDS tile transpose ----------
__global__ void k_zunitT(const float* __restrict__ z, const float* __restrict__ invzn,
                         __hip_bfloat16* __restrict__ zt, int K, int N) {
  __shared__ float tile[32][33];
  int tx = threadIdx.x, ty = threadIdx.y;   // (32,8)
  int c0 = blockIdx.x * 32, r0 = blockIdx.y * 32;
  float inv = invzn[c0 + tx];
  #pragma unroll
  for (int i = 0; i < 4; ++i)
    tile[ty + i * 8][tx] = z[(size_t)(r0 + ty + i * 8) * N + c0 + tx] * inv;
  __syncthreads();
  #pragma unroll
  for (int i = 0; i < 4; ++i)
    zt[(size_t)(c0 + ty + i * 8) * K + r0 + tx] = __float2bfloat16(tile[tx][ty + i * 8]);
}

// force a (uniform) pointer into SGPRs so global_load_lds uses saddr form
__device__ __forceinline__ const char* RFL64(const char* p) {
  unsigned long long b = (unsigned long long)p;
  unsigned int lo = __builtin_amdgcn_readfirstlane((unsigned int)b);
  unsigned int hi = __builtin_amdgcn_readfirstlane((unsigned int)(b >> 32));
  return (const char*)(((unsigned long long)hi << 32) | lo);
}

// ---------- K2: 256x256 bf16 MFMA GEMM, streaming-LDS schedule ----------
// Per K-tile: issue ALL 24 ds_reads in use-order, then all 64 MFMAs with NO
// manual lgkm drains — the compiler inserts counted lgkmcnt per operand
// group (m97 asm evidence), so later reads deliver WHILE earlier MFMAs run
// (LDS pipe streams instead of convoy-stalling). One vmcnt(0)+barrier per
// K-tile; stage kt+2 -> buf D after the barrier (every wave's buf-D reads
// delivered before its MFMAs, hence before the barrier -> WAR-safe).
// vmcnt(0) drains only stages issued a full tile (~2500 cyc) ago: ~free.
// Single-parity fragment regs (~96 VGPR + 128 acc) — no R13 parity arrays.
__global__ __launch_bounds__(512, 1) void k_gemm_dot(
    const __hip_bfloat16* __restrict__ A,   // h: M x K
    const __hip_bfloat16* __restrict__ Bt,  // z_unit^T: N x K
    float* __restrict__ dot, int M, int N, int K) {
  __shared__ __align__(16) char smem[131072];
  const int K2 = K * 2;
  int tid = threadIdx.x, lane = tid & 63, wid = tid >> 6;
  int wm = wid >> 2, wn = wid & 3;

  // bijective XCD swizzle (gridDim.x % 8 == 0 here: 512 blocks)
  int bid = blockIdx.x;
  int cpx = gridDim.x >> 3;
  int swz = (bid & 7) * cpx + (bid >> 3);
  int nbx = N >> 8;
  int bx = swz % nbx, by = swz / nbx;
  int bm0 = by * 256, bn0 = bx * 256;

  // ---- staging: per-lane 32-bit offsets (inverse-swizzled source) ----
  int rr = (tid >> 2) & 15;
  int cbyte = ((tid & 3) * 16) ^ ((rr & 8) << 2);
  int kb = ((tid >> 6) & 1) * 64 + cbyte;          // k-byte within tile [0,128)
  int r0 = ((tid >> 7) << 4) + rr;                 // row (j=0); j=1 adds 64
  unsigned int off0 = (unsigned int)(r0 * K2 + kb);
  unsigned int off1 = off0 + (unsigned int)(64 * K2);
  int ldsW = wid * 1024;                           // linear dest (lane*16 implicit)

  const char* aPan0 = (const char*)A + (size_t)bm0 * K2;
  const char* aPan1 = aPan0 + (size_t)128 * K2;
  const char* bPan0 = (const char*)Bt + (size_t)bn0 * K2;
  const char* bPan1 = bPan0 + (size_t)128 * K2;

  auto STAGE = [&](const char* base, int ldsBase) {
    __builtin_amdgcn_global_load_lds(
        (const __attribute__((address_space(1))) unsigned int*)(base + off0),
        (__attribute__((address_space(3))) unsigned int*)(smem + ldsBase + ldsW), 16, 0, 0);
    __builtin_amdgcn_global_load_lds(
        (const __attribute__((address_space(1))) unsigned int*)(base + off1),
        (__attribute__((address_space(3))) unsigned int*)(smem + ldsBase + ldsW + 8192), 16, 0, 0);
  };

  // ---- LDS read bases (swizzled) ----
  int labase = (lane & 15) * 64 + (((lane >> 4) * 16) ^ ((lane & 8) << 2));
  const char* pA0 = smem + wm * 16384 + labase;
  const char* pA1 = pA0 + 65536;
  const char* pB0 = smem + 32768 + (wn >> 1) * 16384 + (wn & 1) * 8192 + labase;
  const char* pB1 = pB0 + 65536;

  s16x8 av0[4][2], av1[4][2], bv[4][2];
  f32x4 acc[8][4] = {};

  // Reads in USE order: av0, bv01, bv23, av1 — compiler's counted lgkm
  // lets ph0 (av0 x bv01) start after the first 12 deliveries.
#define RD_ALL(D) do { \
    const char* pa_ = ((D) ? pA1 : pA0); \
    const char* pb_ = ((D) ? pB1 : pB0); \
    _Pragma("unroll") for (int i_ = 0; i_ < 4; ++i_) { \
      av0[i_][0] = *(const s16x8*)(pa_ + i_ * 2048); \
      av0[i_][1] = *(const s16x8*)(pa_ + i_ * 2048 + 1024); } \
    _Pragma("unroll") for (int f_ = 0; f_ < 2; ++f_) { \
      bv[f_][0] = *(const s16x8*)(pb_ + f_ * 2048); \
      bv[f_][1] = *(const s16x8*)(pb_ + f_ * 2048 + 1024); } \
    _Pragma("unroll") for (int f_ = 2; f_ < 4; ++f_) { \
      bv[f_][0] = *(const s16x8*)(pb_ + f_ * 2048); \
      bv[f_][1] = *(const s16x8*)(pb_ + f_ * 2048 + 1024); } \
    _Pragma("unroll") for (int i_ = 0; i_ < 4; ++i_) { \
      av1[i_][0] = *(const s16x8*)(pa_ + 8192 + i_ * 2048); \
      av1[i_][1] = *(const s16x8*)(pa_ + 8192 + i_ * 2048 + 1024); } } while (0)

  // MFMA order matches read-delivery order: (av0 x b01), (av0 x b23),
  // (av1 x b01), (av1 x b23)
#define MM_ALL() do { \
    _Pragma("unroll") for (int f_ = 0; f_ < 2; ++f_) \
      _Pragma("unroll") for (int i_ = 0; i_ < 4; ++i_) { \
        acc[i_][f_] = __builtin_amdgcn_mfma_f32_16x16x32_bf16( \
            bv[f_][0], av0[i_][0], acc[i_][f_], 0, 0, 0); \
        acc[i_][f_] = __builtin_amdgcn_mfma_f32_16x16x32_bf16( \
            bv[f_][1], av0[i_][1], acc[i_][f_], 0, 0, 0); } \
    _Pragma("unroll") for (int f_ = 2; f_ < 4; ++f_) \
      _Pragma("unroll") for (int i_ = 0; i_ < 4; ++i_) { \
        acc[i_][f_] = __builtin_amdgcn_mfma_f32_16x16x32_bf16( \
            bv[f_][0], av0[i_][0], acc[i_][f_], 0, 0, 0); \
        acc[i_][f_] = __builtin_amdgcn_mfma_f32_16x16x32_bf16( \
            bv[f_][1], av0[i_][1], acc[i_][f_], 0, 0, 0); } \
    _Pragma("unroll") for (int f_ = 0; f_ < 2; ++f_) \
      _Pragma("unroll") for (int i_ = 0; i_ < 4; ++i_) { \
        acc[4 + i_][f_] = __builtin_amdgcn_mfma_f32_16x16x32_bf16( \
            bv[f_][0], av1[i_][0], acc[4 + i_][f_], 0, 0, 0); \
        acc[4 + i_][f_] = __builtin_amdgcn_mfma_f32_16x16x32_bf16( \
            bv[f_][1], av1[i_][1], acc[4 + i_][f_], 0, 0, 0); } \
    _Pragma("unroll") for (int f_ = 2; f_ < 4; ++f_) \
      _Pragma("unroll") for (int i_ = 0; i_ < 4; ++i_) { \
        acc[4 + i_][f_] = __builtin_amdgcn_mfma_f32_16x16x32_bf16( \
            bv[f_][0], av1[i_][0], acc[4 + i_][f_], 0, 0, 0); \
        acc[4 + i_][f_] = __builtin_amdgcn_mfma_f32_16x16x32_bf16( \
            bv[f_][1], av1[i_][1], acc[4 + i_][f_], 0, 0, 0); } } while (0)

  int NT = K >> 6;   // K-tiles of 64 (assumed even)

  // ---- prologue: stage tile0 (8 loads) + tile1 (8 loads) ----
  {
    const char* a0 = RFL64(aPan0); const char* a1 = RFL64(aPan1);
    const char* b0 = RFL64(bPan0); const char* b1 = RFL64(bPan1);
    STAGE(b0, 32768); STAGE(b1, 49152); STAGE(a0, 0); STAGE(a1, 16384);
  }
  if (NT > 1) {
    const char* a0 = RFL64(aPan0 + 128); const char* a1 = RFL64(aPan1 + 128);
    const char* b0 = RFL64(bPan0 + 128); const char* b1 = RFL64(bPan1 + 128);
    STAGE(b0, 65536 + 32768); STAGE(b1, 65536 + 49152);
    STAGE(a0, 65536); STAGE(a1, 65536 + 16384);
    asm volatile("s_waitcnt vmcnt(8)");
  } else {
    asm volatile("s_waitcnt vmcnt(0)");
  }
  __builtin_amdgcn_s_barrier();

#define KTILE(D, KT) do { \
    bool st_ = ((KT) + 2 < NT); \
    int kOff2_ = ((KT) + 2) << 7; \
    const char* aB0_ = RFL64(aPan0 + kOff2_); \
    const char* aB1_ = RFL64(aPan1 + kOff2_); \
    const char* bB0_ = RFL64(bPan0 + kOff2_); \
    const char* bB1_ = RFL64(bPan1 + kOff2_); \
    RD_ALL(D); \
    MM_ALL(); \
    asm volatile("s_waitcnt vmcnt(0)"); \
    __builtin_amdgcn_s_barrier(); \
    if (st_) { STAGE(bB0_, (D) * 65536 + 32768); STAGE(bB1_, (D) * 65536 + 49152); \
               STAGE(aB0_, (D) * 65536); STAGE(aB1_, (D) * 65536 + 16384); } \
  } while (0)

  for (int kt = 0; kt < NT; kt += 2) {
    KTILE(0, kt);
    KTILE(1, kt + 1);
  }
#undef KTILE
#undef RD_ALL
#undef MM_ALL

  // ---- epilogue: float4 stores (transposed fragment layout) ----
  int ml = lane & 15, ng = lane >> 4;
  #pragma unroll
  for (int fm = 0; fm < 8; ++fm) {
    int row = bm0 + wm * 128 + fm * 16 + ml;
    size_t rowo = (size_t)row * N + bn0 + wn * 64 + ng * 4;
    #pragma unroll
    for (int fn = 0; fn < 4; ++fn) {
      *(f32x4*)(dot + rowo + fn * 16) = acc[fm][fn];
    }
  }
}

// ---------- K3: MLR + ball-lift + logmap0, hw-transcendental, in place ----------
// y = sinh(s*asinh(u)) = 0.5*(w^s - w^(-s)), w = u + sqrt(u^2+1), s = zn2[c].
__global__ void k_mlr_final(float* __restrict__ io, const float* __restrict__ cx2,
                            const float* __restrict__ invomc, const float* __restrict__ zn2,
                            const float* __restrict__ chb, const float* __restrict__ shb,
                            int N) {
  int row = blockIdx.x, t = threadIdx.x;
  float4* ior = (float4*)(io + (size_t)row * N);
  const float4* ch4 = (const float4*)chb;
  const float4* sh4 = (const float4*)shb;
  const float4* z24 = (const float4*)zn2;
  float c2 = cx2[row], inv = invomc[row];
  float opc = 1.f + c2;
  float y[4][4];
  float s = 0.f;
  #pragma unroll
  for (int i = 0; i < 4; ++i) {
    int idx = t + (i << 8);
    float4 d = ior[idx], ch = ch4[idx], sh = sh4[idx], z2 = z24[idx];
    float dq[4] = {d.x, d.y, d.z, d.w};
    float chq[4] = {ch.x, ch.y, ch.z, ch.w};
    float shq[4] = {sh.x, sh.y, sh.z, sh.w};
    float zq[4] = {z2.x, z2.y, z2.z, z2.w};
    #pragma unroll
    for (int q = 0; q < 4; ++q) {
      float u = (2.f * dq[q] * chq[q] - opc * shq[q]) * inv;
      float w = u + sqrtf(fmaf(u, u, 1.f));
      float p = hw_log2(w);
      float tq = zq[q] * p;
      float ep = hw_exp2(tq);
      float em = hw_exp2(-tq);
      float yy = 0.5f * (ep - em);
      y[i][q] = yy;
      s += yy * yy;
    }
  }
  float ny2 = block_reduce_sum_256(s);
  float ny = sqrtf(ny2);
  float sfac = fast_rcp(1.f + sqrtf(1.f + ny2));  // lift: y_ball = sfac*y
  float w = sfac * ny;
  float nw = fmaxf(w, EPSF);
  float tt = fminf(nw, 1.f - EPSF);
  float la = 0.5f * LN2 * hw_log2((1.f + tt) * fast_rcp(1.f - tt));
  float coef = la * sfac * fast_rcp(nw);
  #pragma unroll
  for (int i = 0; i < 4; ++i) {
    int idx = t + (i << 8);
    float4 o;
    o.x = coef * y[i][0]; o.y = coef * y[i][1];
    o.z = coef * y[i][2]; o.w = coef * y[i][3];
    ior[idx] = o;
  }
}

extern "C" void kernel_launch(void* const* d_in, const int* in_sizes, int n_in,
                              void* d_out, int out_size, void* d_ws, size_t ws_size,
                              hipStream_t stream) {
  const float* x    = (const float*)d_in[0];
  const float* z    = (const float*)d_in[1];
  const float* bias = (const float*)d_in[2];
  float* out = (float*)d_out;

  int N = in_sizes[2];           // DOUT = 4096
  int K = in_sizes[1] / N;       // DIN  = 4096
  int M = in_sizes[0] / K;       // B    = 8192

  char* ws = (char*)d_ws;
  size_t o = 0;
  __hip_bfloat16* h  = (__hip_bfloat16*)(ws + o); o += (size_t)M * K * 2;
  __hip_bfloat16* zt = (__hip_bfloat16*)(ws + o); o += (size_t)N * K * 2;
  float* cx2    = (float*)(ws + o); o += (size_t)M * 4;
  float* invomc = (float*)(ws + o); o += (size_t)M * 4;
  float* part   = (float*)(ws + o); o += (size_t)32 * N * 4;
  float* zn2    = (float*)(ws + o); o += (size_t)N * 4;
  float* invzn  = (float*)(ws + o); o += (size_t)N * 4;
  float* chb    = (float*)(ws + o); o += (size_t)N * 4;
  float* shb    = (float*)(ws + o); o += (size_t)N * 4;

  const int NCH = 32;
  k_expmap<<<M, 256, 0, stream>>>(x, h, cx2, invomc, K);
  k_colsq<<<dim3(N / 1024, NCH), 256, 0, stream>>>(z, part, K, N, K / NCH);
  k_colfin<<<N / 256, 256, 0, stream>>>(part, bias, zn2, invzn, chb, shb, N, NCH);
  k_zunitT<<<dim3(N / 32, K / 32), dim3(32, 8), 0, stream>>>(z, invzn, zt, K, N);
  int grid = (M / 256) * (N / 256);
  k_gemm_dot<<<grid, 512, 0, stream>>>(h, zt, out, M, N, K);
  k_mlr_final<<<M, 256, 0, stream>>>(out, cx2, invomc, zn2, chb, shb, N);
}

// Round 15
// 422.254 us; speedup vs baseline: 1.4398x; 1.1224x over previous
//
#include <hip/hip_runtime.h>
#include <hip/hip_bf16.h>
#include <math.h>

#define EPSF 1e-5f
#define LOG2E 1.4426950408889634f
#define LN2 0.6931471805599453f

typedef __attribute__((ext_vector_type(4))) float f32x4;
typedef __attribute__((ext_vector_type(8))) short s16x8;

__device__ __forceinline__ float hw_exp2(float x) { return __builtin_amdgcn_exp2f(x); }
__device__ __forceinline__ float hw_log2(float x) { return __builtin_amdgcn_logf(x); }
__device__ __forceinline__ float fast_rcp(float x) { return __builtin_amdgcn_rcpf(x); }

// ---------- block reduction (256 threads = 4 waves) ----------
__device__ __forceinline__ float block_reduce_sum_256(float s) {
  #pragma unroll
  for (int o = 32; o > 0; o >>= 1) s += __shfl_xor(s, o, 64);
  __shared__ float red[4];
  int lane = threadIdx.x & 63, wid = threadIdx.x >> 6;
  if (lane == 0) red[wid] = s;
  __syncthreads();
  return red[0] + red[1] + red[2] + red[3];
}

__device__ __forceinline__ unsigned short f2bu(float f) {
  __hip_bfloat16 b = __float2bfloat16(f);
  return __builtin_bit_cast(unsigned short, b);
}

// ---------- K0: h = expmap0(x) as bf16; cx2, 1/(1-cx2) per row (float4) ----------
__global__ void k_expmap(const float* __restrict__ x, __hip_bfloat16* __restrict__ h,
                         float* __restrict__ cx2, float* __restrict__ invomc, int K) {
  int row = blockIdx.x, t = threadIdx.x;
  const float4* xr = (const float4*)(x + (size_t)row * K);
  float4 v[4];
  float s = 0.f;
  #pragma unroll
  for (int i = 0; i < 4; ++i) {
    v[i] = xr[t + (i << 8)];
    s += v[i].x * v[i].x + v[i].y * v[i].y + v[i].z * v[i].z + v[i].w * v[i].w;
  }
  float nsq = block_reduce_sum_256(s);
  float n = fmaxf(sqrtf(nsq), EPSF);
  float e2 = hw_exp2(2.f * LOG2E * n);
  float th = 1.f - 2.f * fast_rcp(e2 + 1.f);
  float sc = th * fast_rcp(n);        // tanh(n)/n, rc = 1
  float hn2 = sc * sc * nsq;          // ||h||^2
  float c2 = fminf(hn2, 1.f - EPSF);
  if (t == 0) { cx2[row] = c2; invomc[row] = 1.f / (1.f - c2); }
  ushort4* hr = (ushort4*)(h + (size_t)row * K);
  #pragma unroll
  for (int i = 0; i < 4; ++i) {
    ushort4 o;
    o.x = f2bu(sc * v[i].x); o.y = f2bu(sc * v[i].y);
    o.z = f2bu(sc * v[i].z); o.w = f2bu(sc * v[i].w);
    hr[t + (i << 8)] = o;
  }
}

// ---------- K1a: partial column sum-of-squares of z (float4, deterministic) ----------
__global__ void k_colsq(const float* __restrict__ z, float* __restrict__ part,
                        int K, int N, int rows_per_chunk) {
  int c4 = blockIdx.x * 256 + threadIdx.x;    // float4 column index
  int r0 = blockIdx.y * rows_per_chunk;
  const float4* z4 = (const float4*)z;
  int n4 = N >> 2;
  float4 a = {0.f, 0.f, 0.f, 0.f};
  for (int r = r0; r < r0 + rows_per_chunk; ++r) {
    float4 v = z4[(size_t)r * n4 + c4];
    a.x += v.x * v.x; a.y += v.y * v.y; a.z += v.z * v.z; a.w += v.w * v.w;
  }
  ((float4*)part)[(size_t)blockIdx.y * n4 + c4] = a;
}

// ---------- K1b: finalize per-column scalars ----------
__global__ void k_colfin(const float* __restrict__ part, const float* __restrict__ bias,
                         float* __restrict__ zn2, float* __restrict__ invzn,
                         float* __restrict__ ch, float* __restrict__ sh,
                         int N, int nchunk) {
  int c = blockIdx.x * 256 + threadIdx.x;
  float s = 0.f;
  for (int i = 0; i < nchunk; ++i) s += part[(size_t)i * N + c];
  float zn = fmaxf(sqrtf(s), EPSF);
  zn2[c] = 2.f * zn;
  invzn[c] = 1.f / zn;
  float d = 2.f * bias[c];
  float ep = hw_exp2(LOG2E * d);
  float em = fast_rcp(ep);
  ch[c] = 0.5f * (ep + em);
  sh[c] = 0.5f * (ep - em);
}

// ---------- K1c: z_unit^T (N x K) bf16, LDS tile transpose ----------
__global__ void k_zunitT(const float* __restrict__ z, const float* __restrict__ invzn,
                         __hip_bfloat16* __restrict__ zt, int K, int N) {
  __shared__ float tile[32][33];
  int tx = threadIdx.x, ty = threadIdx.y;   // (32,8)
  int c0 = blockIdx.x * 32, r0 = blockIdx.y * 32;
  float inv = invzn[c0 + tx];
  #pragma unroll
  for (int i = 0; i < 4; ++i)
    tile[ty + i * 8][tx] = z[(size_t)(r0 + ty + i * 8) * N + c0 + tx] * inv;
  __syncthreads();
  #pragma unroll
  for (int i = 0; i < 4; ++i)
    zt[(size_t)(c0 + ty + i * 8) * K + r0 + tx] = __float2bfloat16(tile[tx][ty + i * 8]);
}

// force a (uniform) pointer into SGPRs so global_load_lds uses saddr form
__device__ __forceinline__ const char* RFL64(const char* p) {
  unsigned long long b = (unsigned long long)p;
  unsigned int lo = __builtin_amdgcn_readfirstlane((unsigned int)b);
  unsigned int hi = __builtin_amdgcn_readfirstlane((unsigned int)(b >> 32));
  return (const char*)(((unsigned long long)hi << 32) | lo);
}

// ---------- K2: 256x256 bf16 MFMA GEMM (R12 4-barrier loop, best=263us) ----------
// FUSE=0: write raw f32 dots (R12 path).
// FUSE=1: fused per-element Poincare-MLR y = sinh(zn2*asinh(u)) via hw
//         exp2/log2 (post-loop only, ~10 TRANS ops/elem), stored as bf16
//         (halves epilogue write + k_final read traffic).
template<int FUSE>
__global__ __launch_bounds__(512, 1) void k_gemm_dot(
    const __hip_bfloat16* __restrict__ A,   // h: M x K
    const __hip_bfloat16* __restrict__ Bt,  // z_unit^T: N x K
    float* __restrict__ dotf,               // FUSE=0 out
    unsigned short* __restrict__ ybf,       // FUSE=1 out (bf16 bits)
    const float* __restrict__ cx2, const float* __restrict__ invomc,
    const float* __restrict__ zn2b, const float* __restrict__ chb,
    const float* __restrict__ shb,
    int M, int N, int K) {
  __shared__ __align__(16) char smem[131072];
  const int K2 = K * 2;
  int tid = threadIdx.x, lane = tid & 63, wid = tid >> 6;
  int wm = wid >> 2, wn = wid & 3;

  // bijective XCD swizzle (gridDim.x % 8 == 0 here: 512 blocks)
  int bid = blockIdx.x;
  int cpx = gridDim.x >> 3;
  int swz = (bid & 7) * cpx + (bid >> 3);
  int nbx = N >> 8;
  int bx = swz % nbx, by = swz / nbx;
  int bm0 = by * 256, bn0 = bx * 256;

  // ---- staging: per-lane 32-bit offsets (inverse-swizzled source) ----
  int rr = (tid >> 2) & 15;
  int cbyte = ((tid & 3) * 16) ^ ((rr & 8) << 2);
  int kb = ((tid >> 6) & 1) * 64 + cbyte;          // k-byte within tile [0,128)
  int r0 = ((tid >> 7) << 4) + rr;                 // row (j=0); j=1 adds 64
  unsigned int off0 = (unsigned int)(r0 * K2 + kb);
  unsigned int off1 = off0 + (unsigned int)(64 * K2);
  int ldsW = wid * 1024;                           // linear dest (lane*16 implicit)

  const char* aPan0 = (const char*)A + (size_t)bm0 * K2;
  const char* aPan1 = aPan0 + (size_t)128 * K2;
  const char* bPan0 = (const char*)Bt + (size_t)bn0 * K2;
  const char* bPan1 = bPan0 + (size_t)128 * K2;

  auto STAGE = [&](const char* base, int ldsBase) {
    __builtin_amdgcn_global_load_lds(
        (const __attribute__((address_space(1))) unsigned int*)(base + off0),
        (__attribute__((address_space(3))) unsigned int*)(smem + ldsBase + ldsW), 16, 0, 0);
    __builtin_amdgcn_global_load_lds(
        (const __attribute__((address_space(1))) unsigned int*)(base + off1),
        (__attribute__((address_space(3))) unsigned int*)(smem + ldsBase + ldsW + 8192), 16, 0, 0);
  };

  // ---- LDS read bases (swizzled) ----
  int labase = (lane & 15) * 64 + (((lane >> 4) * 16) ^ ((lane & 8) << 2));
  const char* pA0 = smem + wm * 16384 + labase;
  const char* pA1 = pA0 + 65536;
  const char* pB0 = smem + 32768 + (wn >> 1) * 16384 + (wn & 1) * 8192 + labase;
  const char* pB1 = pB0 + 65536;

  s16x8 av0[4][2], av1[4][2], bv[4][2];
  f32x4 acc[8][4] = {};

#define RDA0(D) do { const char* p_ = ((D) ? pA1 : pA0); \
    _Pragma("unroll") for (int i_ = 0; i_ < 4; ++i_) { \
      av0[i_][0] = *(const s16x8*)(p_ + i_ * 2048); \
      av0[i_][1] = *(const s16x8*)(p_ + i_ * 2048 + 1024); } } while (0)
#define RDA1(D) do { const char* p_ = ((D) ? pA1 : pA0); \
    _Pragma("unroll") for (int i_ = 0; i_ < 4; ++i_) { \
      av1[i_][0] = *(const s16x8*)(p_ + 8192 + i_ * 2048); \
      av1[i_][1] = *(const s16x8*)(p_ + 8192 + i_ * 2048 + 1024); } } while (0)
#define RDB01(D) do { const char* p_ = ((D) ? pB1 : pB0); \
    _Pragma("unroll") for (int f_ = 0; f_ < 2; ++f_) { \
      bv[f_][0] = *(const s16x8*)(p_ + f_ * 2048); \
      bv[f_][1] = *(const s16x8*)(p_ + f_ * 2048 + 1024); } } while (0)
#define RDB23(D) do { const char* p_ = ((D) ? pB1 : pB0); \
    _Pragma("unroll") for (int f_ = 2; f_ < 4; ++f_) { \
      bv[f_][0] = *(const s16x8*)(p_ + f_ * 2048); \
      bv[f_][1] = *(const s16x8*)(p_ + f_ * 2048 + 1024); } } while (0)
#define MMQ(AV, NQ) do { \
    _Pragma("unroll") for (int i_ = 0; i_ < 4; ++i_) \
      _Pragma("unroll") for (int jn_ = 0; jn_ < 2; ++jn_) { \
        int fr_ = (AV) * 4 + i_, fc_ = (NQ) * 2 + jn_; \
        acc[fr_][fc_] = __builtin_amdgcn_mfma_f32_16x16x32_bf16( \
            bv[fc_][0], ((AV) ? av1 : av0)[i_][0], acc[fr_][fc_], 0, 0, 0); \
        acc[fr_][fc_] = __builtin_amdgcn_mfma_f32_16x16x32_bf16( \
            bv[fc_][1], ((AV) ? av1 : av0)[i_][1], acc[fr_][fc_], 0, 0, 0); } } while (0)

  int NT = K >> 6;   // K-tiles of 64 (assumed even)

  // ---- prologue: stage tile0 (8 loads) + tile1 (8 loads) ----
  {
    const char* a0 = RFL64(aPan0); const char* a1 = RFL64(aPan1);
    const char* b0 = RFL64(bPan0); const char* b1 = RFL64(bPan1);
    STAGE(b0, 32768); STAGE(b1, 49152); STAGE(a0, 0); STAGE(a1, 16384);
  }
  if (NT > 1) {
    const char* a0 = RFL64(aPan0 + 128); const char* a1 = RFL64(aPan1 + 128);
    const char* b0 = RFL64(bPan0 + 128); const char* b1 = RFL64(bPan1 + 128);
    STAGE(b0, 65536 + 32768); STAGE(b1, 65536 + 49152);
    STAGE(a0, 65536); STAGE(a1, 65536 + 16384);
    asm volatile("s_waitcnt vmcnt(8)");
  } else {
    asm volatile("s_waitcnt vmcnt(0)");
  }
  __builtin_amdgcn_s_barrier();

#define KTILE(D, KT) do { \
    bool pf_ = ((KT) + 2 < NT); \
    int kOff2_ = ((KT) + 2) << 7; \
    const char* aB0_ = RFL64(aPan0 + kOff2_); \
    const char* aB1_ = RFL64(aPan1 + kOff2_); \
    const char* bB0_ = RFL64(bPan0 + kOff2_); \
    const char* bB1_ = RFL64(bPan1 + kOff2_); \
    /* p0: reads av0+bv01; MFMA (0,0) */ \
    RDA0(D); RDB01(D); \
    asm volatile("s_waitcnt lgkmcnt(0)"); \
    __builtin_amdgcn_s_setprio(1); MMQ(0, 0); __builtin_amdgcn_s_setprio(0); \
    __builtin_amdgcn_s_barrier(); \
    /* p1: reads av1+bv23; MFMA (0,1) */ \
    RDA1(D); RDB23(D); \
    asm volatile("s_waitcnt lgkmcnt(0)"); \
    __builtin_amdgcn_s_setprio(1); MMQ(0, 1); __builtin_amdgcn_s_setprio(0); \
    __builtin_amdgcn_s_barrier(); \
    /* p2: MFMA (1,0) (all operands in regs) */ \
    __builtin_amdgcn_s_setprio(1); MMQ(1, 0); __builtin_amdgcn_s_setprio(0); \
    __builtin_amdgcn_s_barrier(); \
    /* p3: stage all 4 half-tiles (kt+2 -> buf D); MFMA (1,1) */ \
    if (pf_) { STAGE(bB0_, (D) * 65536 + 32768); STAGE(bB1_, (D) * 65536 + 49152); \
               STAGE(aB0_, (D) * 65536); STAGE(aB1_, (D) * 65536 + 16384); } \
    __builtin_amdgcn_s_setprio(1); MMQ(1, 1); __builtin_amdgcn_s_setprio(0); \
    if (pf_) { asm volatile("s_waitcnt vmcnt(8)"); } \
    else     { asm volatile("s_waitcnt vmcnt(0)"); } \
    __builtin_amdgcn_s_barrier(); \
  } while (0)

  for (int kt = 0; kt < NT; kt += 2) {
    KTILE(0, kt);
    KTILE(1, kt + 1);
  }
#undef KTILE
#undef RDA0
#undef RDA1
#undef RDB01
#undef RDB23
#undef MMQ

  // ---- epilogue (transposed fragment: lane&15 = M-row, ng*4+j = N-cols) ----
  int ml = lane & 15, ng = lane >> 4;
  int cbase = bn0 + wn * 64 + ng * 4;
  if constexpr (FUSE == 0) {
    #pragma unroll
    for (int fm = 0; fm < 8; ++fm) {
      int row = bm0 + wm * 128 + fm * 16 + ml;
      size_t rowo = (size_t)row * N + cbase;
      #pragma unroll
      for (int fn = 0; fn < 4; ++fn) {
        *(f32x4*)(dotf + rowo + fn * 16) = acc[fm][fn];
      }
    }
  } else {
    f32x4 chv[4], shv[4], znv[4];
    #pragma unroll
    for (int fn = 0; fn < 4; ++fn) {
      chv[fn] = *(const f32x4*)(chb + cbase + fn * 16);
      shv[fn] = *(const f32x4*)(shb + cbase + fn * 16);
      znv[fn] = *(const f32x4*)(zn2b + cbase + fn * 16);
    }
    #pragma unroll
    for (int fm = 0; fm < 8; ++fm) {
      int row = bm0 + wm * 128 + fm * 16 + ml;
      float c2 = cx2[row], inv = invomc[row];
      float opc = 1.f + c2;
      size_t rowo = (size_t)row * N + cbase;
      #pragma unroll
      for (int fn = 0; fn < 4; ++fn) {
        ushort4 pk;
        #pragma unroll
        for (int j = 0; j < 4; ++j) {
          float u = (2.f * acc[fm][fn][j] * chv[fn][j] - opc * shv[fn][j]) * inv;
          float wv = u + sqrtf(fmaf(u, u, 1.f));
          float tq = znv[fn][j] * hw_log2(wv);
          float yy = 0.5f * (hw_exp2(tq) - hw_exp2(-tq));
          ((unsigned short*)&pk)[j] = f2bu(yy);
        }
        *(ushort4*)(ybf + rowo + fn * 16) = pk;
      }
    }
  }
}

// ---------- K3a (FUSE=0 fallback): MLR + ball-lift + logmap0, in place ----------
__global__ void k_mlr_final(float* __restrict__ io, const float* __restrict__ cx2,
                            const float* __restrict__ invomc, const float* __restrict__ zn2,
                            const float* __restrict__ chb, const float* __restrict__ shb,
                            int N) {
  int row = blockIdx.x, t = threadIdx.x;
  float4* ior = (float4*)(io + (size_t)row * N);
  const float4* ch4 = (const float4*)chb;
  const float4* sh4 = (const float4*)shb;
  const float4* z24 = (const float4*)zn2;
  float c2 = cx2[row], inv = invomc[row];
  float opc = 1.f + c2;
  float y[4][4];
  float s = 0.f;
  #pragma unroll
  for (int i = 0; i < 4; ++i) {
    int idx = t + (i << 8);
    float4 d = ior[idx], ch = ch4[idx], sh = sh4[idx], z2 = z24[idx];
    float dq[4] = {d.x, d.y, d.z, d.w};
    float chq[4] = {ch.x, ch.y, ch.z, ch.w};
    float shq[4] = {sh.x, sh.y, sh.z, sh.w};
    float zq[4] = {z2.x, z2.y, z2.z, z2.w};
    #pragma unroll
    for (int q = 0; q < 4; ++q) {
      float u = (2.f * dq[q] * chq[q] - opc * shq[q]) * inv;
      float w = u + sqrtf(fmaf(u, u, 1.f));
      float tq = zq[q] * hw_log2(w);
      float yy = 0.5f * (hw_exp2(tq) - hw_exp2(-tq));
      y[i][q] = yy;
      s += yy * yy;
    }
  }
  float ny2 = block_reduce_sum_256(s);
  float ny = sqrtf(ny2);
  float sfac = fast_rcp(1.f + sqrtf(1.f + ny2));
  float w = sfac * ny;
  float nw = fmaxf(w, EPSF);
  float tt = fminf(nw, 1.f - EPSF);
  float la = 0.5f * LN2 * hw_log2((1.f + tt) * fast_rcp(1.f - tt));
  float coef = la * sfac * fast_rcp(nw);
  #pragma unroll
  for (int i = 0; i < 4; ++i) {
    int idx = t + (i << 8);
    float4 o;
    o.x = coef * y[i][0]; o.y = coef * y[i][1];
    o.z = coef * y[i][2]; o.w = coef * y[i][3];
    ior[idx] = o;
  }
}

// ---------- K3b (FUSE=1): row norm + ball-lift + logmap0 from bf16 y ----------
__global__ void k_final(const unsigned short* __restrict__ y, float* __restrict__ out,
                        int N) {
  int row = blockIdx.x, t = threadIdx.x;
  const s16x8* yr = (const s16x8*)(y + (size_t)row * N);
  float yv[16];
  float s = 0.f;
  #pragma unroll
  for (int i = 0; i < 2; ++i) {
    s16x8 v = yr[t + (i << 8)];
    #pragma unroll
    for (int j = 0; j < 8; ++j) {
      unsigned int b = ((unsigned int)(unsigned short)v[j]) << 16;
      float f = __builtin_bit_cast(float, b);
      yv[i * 8 + j] = f;
      s += f * f;
    }
  }
  float ny2 = block_reduce_sum_256(s);
  float ny = sqrtf(ny2);
  float sfac = fast_rcp(1.f + sqrtf(1.f + ny2));  // lift: y_ball = sfac*y
  float w = sfac * ny;
  float nw = fmaxf(w, EPSF);
  float tt = fminf(nw, 1.f - EPSF);
  float la = 0.5f * LN2 * hw_log2((1.f + tt) * fast_rcp(1.f - tt));
  float coef = la * sfac * fast_rcp(nw);
  #pragma unroll
  for (int i = 0; i < 2; ++i) {
    size_t base = (size_t)row * N + ((size_t)t + (i << 8)) * 8;
    float4 o0, o1;
    o0.x = coef * yv[i * 8 + 0]; o0.y = coef * yv[i * 8 + 1];
    o0.z = coef * yv[i * 8 + 2]; o0.w = coef * yv[i * 8 + 3];
    o1.x = coef * yv[i * 8 + 4]; o1.y = coef * yv[i * 8 + 5];
    o1.z = coef * yv[i * 8 + 6]; o1.w = coef * yv[i * 8 + 7];
    *(float4*)(out + base) = o0;
    *(float4*)(out + base + 4) = o1;
  }
}

extern "C" void kernel_launch(void* const* d_in, const int* in_sizes, int n_in,
                              void* d_out, int out_size, void* d_ws, size_t ws_size,
                              hipStream_t stream) {
  const float* x    = (const float*)d_in[0];
  const float* z    = (const float*)d_in[1];
  const float* bias = (const float*)d_in[2];
  float* out = (float*)d_out;

  int N = in_sizes[2];           // DOUT = 4096
  int K = in_sizes[1] / N;       // DIN  = 4096
  int M = in_sizes[0] / K;       // B    = 8192

  char* ws = (char*)d_ws;
  size_t o = 0;
  __hip_bfloat16* h  = (__hip_bfloat16*)(ws + o); o += (size_t)M * K * 2;
  __hip_bfloat16* zt = (__hip_bfloat16*)(ws + o); o += (size_t)N * K * 2;
  float* cx2    = (float*)(ws + o); o += (size_t)M * 4;
  float* invomc = (float*)(ws + o); o += (size_t)M * 4;
  float* part   = (float*)(ws + o); o += (size_t)32 * N * 4;
  float* zn2    = (float*)(ws + o); o += (size_t)N * 4;
  float* invzn  = (float*)(ws + o); o += (size_t)N * 4;
  float* chb    = (float*)(ws + o); o += (size_t)N * 4;
  float* shb    = (float*)(ws + o); o += (size_t)N * 4;
  // bf16 y intermediate (fused path) — only if ws has room
  size_t yBytes = (size_t)M * N * 2;
  bool fuse = (ws_size >= o + yBytes);
  unsigned short* ybf = (unsigned short*)(ws + o);

  const int NCH = 32;
  k_expmap<<<M, 256, 0, stream>>>(x, h, cx2, invomc, K);
  k_colsq<<<dim3(N / 1024, NCH), 256, 0, stream>>>(z, part, K, N, K / NCH);
  k_colfin<<<N / 256, 256, 0, stream>>>(part, bias, zn2, invzn, chb, shb, N, NCH);
  k_zunitT<<<dim3(N / 32, K / 32), dim3(32, 8), 0, stream>>>(z, invzn, zt, K, N);
  int grid = (M / 256) * (N / 256);
  if (fuse) {
    k_gemm_dot<1><<<grid, 512, 0, stream>>>(h, zt, out, ybf, cx2, invomc, zn2, chb, shb,
                                            M, N, K);
    k_final<<<M, 256, 0, stream>>>(ybf, out, N);
  } else {
    k_gemm_dot<0><<<grid, 512, 0, stream>>>(h, zt, out, ybf, cx2, invomc, zn2, chb, shb,
                                            M, N, K);
    k_mlr_final<<<M, 256, 0, stream>>>(out, cx2, invomc, zn2, chb, shb, N);
  }
}

// Round 16
// 417.003 us; speedup vs baseline: 1.4579x; 1.0126x over previous
//
#include <hip/hip_runtime.h>
#include <hip/hip_bf16.h>
#include <math.h>

#define EPSF 1e-5f
#define LOG2E 1.4426950408889634f
#define LN2 0.6931471805599453f

typedef __attribute__((ext_vector_type(4))) float f32x4;
typedef __attribute__((ext_vector_type(8))) short s16x8;

__device__ __forceinline__ float hw_exp2(float x) { return __builtin_amdgcn_exp2f(x); }
__device__ __forceinline__ float hw_log2(float x) { return __builtin_amdgcn_logf(x); }
__device__ __forceinline__ float fast_rcp(float x) { return __builtin_amdgcn_rcpf(x); }

// ---------- block reduction (256 threads = 4 waves) ----------
__device__ __forceinline__ float block_reduce_sum_256(float s) {
  #pragma unroll
  for (int o = 32; o > 0; o >>= 1) s += __shfl_xor(s, o, 64);
  __shared__ float red[4];
  int lane = threadIdx.x & 63, wid = threadIdx.x >> 6;
  if (lane == 0) red[wid] = s;
  __syncthreads();
  return red[0] + red[1] + red[2] + red[3];
}

__device__ __forceinline__ unsigned short f2bu(float f) {
  __hip_bfloat16 b = __float2bfloat16(f);
  return __builtin_bit_cast(unsigned short, b);
}

// ---------- K0: h = expmap0(x) as bf16; cx2, 1/(1-cx2) per row (float4) ----------
__global__ void k_expmap(const float* __restrict__ x, __hip_bfloat16* __restrict__ h,
                         float* __restrict__ cx2, float* __restrict__ invomc, int K) {
  int row = blockIdx.x, t = threadIdx.x;
  const float4* xr = (const float4*)(x + (size_t)row * K);
  float4 v[4];
  float s = 0.f;
  #pragma unroll
  for (int i = 0; i < 4; ++i) {
    v[i] = xr[t + (i << 8)];
    s += v[i].x * v[i].x + v[i].y * v[i].y + v[i].z * v[i].z + v[i].w * v[i].w;
  }
  float nsq = block_reduce_sum_256(s);
  float n = fmaxf(sqrtf(nsq), EPSF);
  float e2 = hw_exp2(2.f * LOG2E * n);
  float th = 1.f - 2.f * fast_rcp(e2 + 1.f);
  float sc = th * fast_rcp(n);        // tanh(n)/n, rc = 1
  float hn2 = sc * sc * nsq;          // ||h||^2
  float c2 = fminf(hn2, 1.f - EPSF);
  if (t == 0) { cx2[row] = c2; invomc[row] = 1.f / (1.f - c2); }
  ushort4* hr = (ushort4*)(h + (size_t)row * K);
  #pragma unroll
  for (int i = 0; i < 4; ++i) {
    ushort4 o;
    o.x = f2bu(sc * v[i].x); o.y = f2bu(sc * v[i].y);
    o.z = f2bu(sc * v[i].z); o.w = f2bu(sc * v[i].w);
    hr[t + (i << 8)] = o;
  }
}

// ---------- K1a: partial column sum-of-squares of z (float4, deterministic) ----------
__global__ void k_colsq(const float* __restrict__ z, float* __restrict__ part,
                        int K, int N, int rows_per_chunk) {
  int c4 = blockIdx.x * 256 + threadIdx.x;    // float4 column index
  int r0 = blockIdx.y * rows_per_chunk;
  const float4* z4 = (const float4*)z;
  int n4 = N >> 2;
  float4 a = {0.f, 0.f, 0.f, 0.f};
  for (int r = r0; r < r0 + rows_per_chunk; ++r) {
    float4 v = z4[(size_t)r * n4 + c4];
    a.x += v.x * v.x; a.y += v.y * v.y; a.z += v.z * v.z; a.w += v.w * v.w;
  }
  ((float4*)part)[(size_t)blockIdx.y * n4 + c4] = a;
}

// ---------- K1b: finalize per-column scalars ----------
__global__ void k_colfin(const float* __restrict__ part, const float* __restrict__ bias,
                         float* __restrict__ zn2, float* __restrict__ invzn,
                         float* __restrict__ ch, float* __restrict__ sh,
                         int N, int nchunk) {
  int c = blockIdx.x * 256 + threadIdx.x;
  float s = 0.f;
  for (int i = 0; i < nchunk; ++i) s += part[(size_t)i * N + c];
  float zn = fmaxf(sqrtf(s), EPSF);
  zn2[c] = 2.f * zn;
  invzn[c] = 1.f / zn;
  float d = 2.f * bias[c];
  float ep = hw_exp2(LOG2E * d);
  float em = fast_rcp(ep);
  ch[c] = 0.5f * (ep + em);
  sh[c] = 0.5f * (ep - em);
}

// ---------- K1c: z_unit^T (N x K) bf16, LDS tile transpose ----------
__global__ void k_zunitT(const float* __restrict__ z, const float* __restrict__ invzn,
                         __hip_bfloat16* __restrict__ zt, int K, int N) {
  __shared__ float tile[32][33];
  int tx = threadIdx.x, ty = threadIdx.y;   // (32,8)
  int c0 = blockIdx.x * 32, r0 = blockIdx.y * 32;
  float inv = invzn[c0 + tx];
  #pragma unroll
  for (int i = 0; i < 4; ++i)
    tile[ty + i * 8][tx] = z[(size_t)(r0 + ty + i * 8) * N + c0 + tx] * inv;
  __syncthreads();
  #pragma unroll
  for (int i = 0; i < 4; ++i)
    zt[(size_t)(c0 + ty + i * 8) * K + r0 + tx] = __float2bfloat16(tile[tx][ty + i * 8]);
}

// force a (uniform) pointer into SGPRs so global_load_lds uses saddr form
__device__ __forceinline__ const char* RFL64(const char* p) {
  unsigned long long b = (unsigned long long)p;
  unsigned int lo = __builtin_amdgcn_readfirstlane((unsigned int)b);
  unsigned int hi = __builtin_amdgcn_readfirstlane((unsigned int)(b >> 32));
  return (const char*)(((unsigned long long)hi << 32) | lo);
}

// ---------- K2: 256x256 bf16 MFMA GEMM (R12 4-barrier loop, best=263us) ----------
// BF16OUT=0: f32 dots to dotf (R12 exact). BF16OUT=1: bf16 dots to ybf —
// conversion-only epilogue (no transcendentals: R15 showed in-GEMM TRANS
// costs what it saves), halves dot-stream traffic.
template<int BF16OUT>
__global__ __launch_bounds__(512, 1) void k_gemm_dot(
    const __hip_bfloat16* __restrict__ A,   // h: M x K
    const __hip_bfloat16* __restrict__ Bt,  // z_unit^T: N x K
    float* __restrict__ dotf,
    unsigned short* __restrict__ ybf,
    int M, int N, int K) {
  __shared__ __align__(16) char smem[131072];
  const int K2 = K * 2;
  int tid = threadIdx.x, lane = tid & 63, wid = tid >> 6;
  int wm = wid >> 2, wn = wid & 3;

  // bijective XCD swizzle (gridDim.x % 8 == 0 here: 512 blocks)
  int bid = blockIdx.x;
  int cpx = gridDim.x >> 3;
  int swz = (bid & 7) * cpx + (bid >> 3);
  int nbx = N >> 8;
  int bx = swz % nbx, by = swz / nbx;
  int bm0 = by * 256, bn0 = bx * 256;

  // ---- staging: per-lane 32-bit offsets (inverse-swizzled source) ----
  int rr = (tid >> 2) & 15;
  int cbyte = ((tid & 3) * 16) ^ ((rr & 8) << 2);
  int kb = ((tid >> 6) & 1) * 64 + cbyte;          // k-byte within tile [0,128)
  int r0 = ((tid >> 7) << 4) + rr;                 // row (j=0); j=1 adds 64
  unsigned int off0 = (unsigned int)(r0 * K2 + kb);
  unsigned int off1 = off0 + (unsigned int)(64 * K2);
  int ldsW = wid * 1024;                           // linear dest (lane*16 implicit)

  const char* aPan0 = (const char*)A + (size_t)bm0 * K2;
  const char* aPan1 = aPan0 + (size_t)128 * K2;
  const char* bPan0 = (const char*)Bt + (size_t)bn0 * K2;
  const char* bPan1 = bPan0 + (size_t)128 * K2;

  auto STAGE = [&](const char* base, int ldsBase) {
    __builtin_amdgcn_global_load_lds(
        (const __attribute__((address_space(1))) unsigned int*)(base + off0),
        (__attribute__((address_space(3))) unsigned int*)(smem + ldsBase + ldsW), 16, 0, 0);
    __builtin_amdgcn_global_load_lds(
        (const __attribute__((address_space(1))) unsigned int*)(base + off1),
        (__attribute__((address_space(3))) unsigned int*)(smem + ldsBase + ldsW + 8192), 16, 0, 0);
  };

  // ---- LDS read bases (swizzled) ----
  int labase = (lane & 15) * 64 + (((lane >> 4) * 16) ^ ((lane & 8) << 2));
  const char* pA0 = smem + wm * 16384 + labase;
  const char* pA1 = pA0 + 65536;
  const char* pB0 = smem + 32768 + (wn >> 1) * 16384 + (wn & 1) * 8192 + labase;
  const char* pB1 = pB0 + 65536;

  s16x8 av0[4][2], av1[4][2], bv[4][2];
  f32x4 acc[8][4] = {};

#define RDA0(D) do { const char* p_ = ((D) ? pA1 : pA0); \
    _Pragma("unroll") for (int i_ = 0; i_ < 4; ++i_) { \
      av0[i_][0] = *(const s16x8*)(p_ + i_ * 2048); \
      av0[i_][1] = *(const s16x8*)(p_ + i_ * 2048 + 1024); } } while (0)
#define RDA1(D) do { const char* p_ = ((D) ? pA1 : pA0); \
    _Pragma("unroll") for (int i_ = 0; i_ < 4; ++i_) { \
      av1[i_][0] = *(const s16x8*)(p_ + 8192 + i_ * 2048); \
      av1[i_][1] = *(const s16x8*)(p_ + 8192 + i_ * 2048 + 1024); } } while (0)
#define RDB01(D) do { const char* p_ = ((D) ? pB1 : pB0); \
    _Pragma("unroll") for (int f_ = 0; f_ < 2; ++f_) { \
      bv[f_][0] = *(const s16x8*)(p_ + f_ * 2048); \
      bv[f_][1] = *(const s16x8*)(p_ + f_ * 2048 + 1024); } } while (0)
#define RDB23(D) do { const char* p_ = ((D) ? pB1 : pB0); \
    _Pragma("unroll") for (int f_ = 2; f_ < 4; ++f_) { \
      bv[f_][0] = *(const s16x8*)(p_ + f_ * 2048); \
      bv[f_][1] = *(const s16x8*)(p_ + f_ * 2048 + 1024); } } while (0)
#define MMQ(AV, NQ) do { \
    _Pragma("unroll") for (int i_ = 0; i_ < 4; ++i_) \
      _Pragma("unroll") for (int jn_ = 0; jn_ < 2; ++jn_) { \
        int fr_ = (AV) * 4 + i_, fc_ = (NQ) * 2 + jn_; \
        acc[fr_][fc_] = __builtin_amdgcn_mfma_f32_16x16x32_bf16( \
            bv[fc_][0], ((AV) ? av1 : av0)[i_][0], acc[fr_][fc_], 0, 0, 0); \
        acc[fr_][fc_] = __builtin_amdgcn_mfma_f32_16x16x32_bf16( \
            bv[fc_][1], ((AV) ? av1 : av0)[i_][1], acc[fr_][fc_], 0, 0, 0); } } while (0)

  int NT = K >> 6;   // K-tiles of 64 (assumed even)

  // ---- prologue: stage tile0 (8 loads) + tile1 (8 loads) ----
  {
    const char* a0 = RFL64(aPan0); const char* a1 = RFL64(aPan1);
    const char* b0 = RFL64(bPan0); const char* b1 = RFL64(bPan1);
    STAGE(b0, 32768); STAGE(b1, 49152); STAGE(a0, 0); STAGE(a1, 16384);
  }
  if (NT > 1) {
    const char* a0 = RFL64(aPan0 + 128); const char* a1 = RFL64(aPan1 + 128);
    const char* b0 = RFL64(bPan0 + 128); const char* b1 = RFL64(bPan1 + 128);
    STAGE(b0, 65536 + 32768); STAGE(b1, 65536 + 49152);
    STAGE(a0, 65536); STAGE(a1, 65536 + 16384);
    asm volatile("s_waitcnt vmcnt(8)");
  } else {
    asm volatile("s_waitcnt vmcnt(0)");
  }
  __builtin_amdgcn_s_barrier();

#define KTILE(D, KT) do { \
    bool pf_ = ((KT) + 2 < NT); \
    int kOff2_ = ((KT) + 2) << 7; \
    const char* aB0_ = RFL64(aPan0 + kOff2_); \
    const char* aB1_ = RFL64(aPan1 + kOff2_); \
    const char* bB0_ = RFL64(bPan0 + kOff2_); \
    const char* bB1_ = RFL64(bPan1 + kOff2_); \
    /* p0: reads av0+bv01; MFMA (0,0) */ \
    RDA0(D); RDB01(D); \
    asm volatile("s_waitcnt lgkmcnt(0)"); \
    __builtin_amdgcn_s_setprio(1); MMQ(0, 0); __builtin_amdgcn_s_setprio(0); \
    __builtin_amdgcn_s_barrier(); \
    /* p1: reads av1+bv23; MFMA (0,1) */ \
    RDA1(D); RDB23(D); \
    asm volatile("s_waitcnt lgkmcnt(0)"); \
    __builtin_amdgcn_s_setprio(1); MMQ(0, 1); __builtin_amdgcn_s_setprio(0); \
    __builtin_amdgcn_s_barrier(); \
    /* p2: MFMA (1,0) (all operands in regs) */ \
    __builtin_amdgcn_s_setprio(1); MMQ(1, 0); __builtin_amdgcn_s_setprio(0); \
    __builtin_amdgcn_s_barrier(); \
    /* p3: stage all 4 half-tiles (kt+2 -> buf D); MFMA (1,1) */ \
    if (pf_) { STAGE(bB0_, (D) * 65536 + 32768); STAGE(bB1_, (D) * 65536 + 49152); \
               STAGE(aB0_, (D) * 65536); STAGE(aB1_, (D) * 65536 + 16384); } \
    __builtin_amdgcn_s_setprio(1); MMQ(1, 1); __builtin_amdgcn_s_setprio(0); \
    if (pf_) { asm volatile("s_waitcnt vmcnt(8)"); } \
    else     { asm volatile("s_waitcnt vmcnt(0)"); } \
    __builtin_amdgcn_s_barrier(); \
  } while (0)

  for (int kt = 0; kt < NT; kt += 2) {
    KTILE(0, kt);
    KTILE(1, kt + 1);
  }
#undef KTILE
#undef RDA0
#undef RDA1
#undef RDB01
#undef RDB23
#undef MMQ

  // ---- epilogue (transposed fragment: lane&15 = M-row, ng*4+j = N-cols) ----
  int ml = lane & 15, ng = lane >> 4;
  int cbase = bn0 + wn * 64 + ng * 4;
  #pragma unroll
  for (int fm = 0; fm < 8; ++fm) {
    int row = bm0 + wm * 128 + fm * 16 + ml;
    size_t rowo = (size_t)row * N + cbase;
    #pragma unroll
    for (int fn = 0; fn < 4; ++fn) {
      if constexpr (BF16OUT == 0) {
        *(f32x4*)(dotf + rowo + fn * 16) = acc[fm][fn];
      } else {
        ushort4 pk;
        pk.x = f2bu(acc[fm][fn][0]); pk.y = f2bu(acc[fm][fn][1]);
        pk.z = f2bu(acc[fm][fn][2]); pk.w = f2bu(acc[fm][fn][3]);
        *(ushort4*)(ybf + rowo + fn * 16) = pk;
      }
    }
  }
}

// ---------- K3a (fallback): MLR + ball-lift + logmap0 from f32 dots, in place ----------
__global__ void k_mlr_final(float* __restrict__ io, const float* __restrict__ cx2,
                            const float* __restrict__ invomc, const float* __restrict__ zn2,
                            const float* __restrict__ chb, const float* __restrict__ shb,
                            int N) {
  int row = blockIdx.x, t = threadIdx.x;
  float4* ior = (float4*)(io + (size_t)row * N);
  const float4* ch4 = (const float4*)chb;
  const float4* sh4 = (const float4*)shb;
  const float4* z24 = (const float4*)zn2;
  float c2 = cx2[row], inv = invomc[row];
  float opc = 1.f + c2;
  float y[4][4];
  float s = 0.f;
  #pragma unroll
  for (int i = 0; i < 4; ++i) {
    int idx = t + (i << 8);
    float4 d = ior[idx], ch = ch4[idx], sh = sh4[idx], z2 = z24[idx];
    float dq[4] = {d.x, d.y, d.z, d.w};
    float chq[4] = {ch.x, ch.y, ch.z, ch.w};
    float shq[4] = {sh.x, sh.y, sh.z, sh.w};
    float zq[4] = {z2.x, z2.y, z2.z, z2.w};
    #pragma unroll
    for (int q = 0; q < 4; ++q) {
      float u = (2.f * dq[q] * chq[q] - opc * shq[q]) * inv;
      float w = u + sqrtf(fmaf(u, u, 1.f));
      float tq = zq[q] * hw_log2(w);
      float yy = 0.5f * (hw_exp2(tq) - hw_exp2(-tq));
      y[i][q] = yy;
      s += yy * yy;
    }
  }
  float ny2 = block_reduce_sum_256(s);
  float ny = sqrtf(ny2);
  float sfac = fast_rcp(1.f + sqrtf(1.f + ny2));
  float w = sfac * ny;
  float nw = fmaxf(w, EPSF);
  float tt = fminf(nw, 1.f - EPSF);
  float la = 0.5f * LN2 * hw_log2((1.f + tt) * fast_rcp(1.f - tt));
  float coef = la * sfac * fast_rcp(nw);
  #pragma unroll
  for (int i = 0; i < 4; ++i) {
    int idx = t + (i << 8);
    float4 o;
    o.x = coef * y[i][0]; o.y = coef * y[i][1];
    o.z = coef * y[i][2]; o.w = coef * y[i][3];
    ior[idx] = o;
  }
}

// ---------- K3b: MLR + ball-lift + logmap0 from bf16 dots -> f32 out ----------
__global__ void k_mlr_bf16(const unsigned short* __restrict__ dot, float* __restrict__ out,
                           const float* __restrict__ cx2, const float* __restrict__ invomc,
                           const float* __restrict__ zn2, const float* __restrict__ chb,
                           const float* __restrict__ shb, int N) {
  int row = blockIdx.x, t = threadIdx.x;
  const s16x8* dr = (const s16x8*)(dot + (size_t)row * N);
  float c2 = cx2[row], inv = invomc[row];
  float opc = 1.f + c2;
  float y[16];
  float s = 0.f;
  #pragma unroll
  for (int i = 0; i < 2; ++i) {
    s16x8 v = dr[t + (i << 8)];
    int ebase = ((int)t + (i << 8)) * 8;
    #pragma unroll
    for (int j = 0; j < 8; ++j) {
      unsigned int b = ((unsigned int)(unsigned short)v[j]) << 16;
      float dq = __builtin_bit_cast(float, b);
      int c = ebase + j;
      float u = (2.f * dq * chb[c] - opc * shb[c]) * inv;
      float w = u + sqrtf(fmaf(u, u, 1.f));
      float tq = zn2[c] * hw_log2(w);
      float yy = 0.5f * (hw_exp2(tq) - hw_exp2(-tq));
      y[i * 8 + j] = yy;
      s += yy * yy;
    }
  }
  float ny2 = block_reduce_sum_256(s);
  float ny = sqrtf(ny2);
  float sfac = fast_rcp(1.f + sqrtf(1.f + ny2));  // lift: y_ball = sfac*y
  float w = sfac * ny;
  float nw = fmaxf(w, EPSF);
  float tt = fminf(nw, 1.f - EPSF);
  float la = 0.5f * LN2 * hw_log2((1.f + tt) * fast_rcp(1.f - tt));
  float coef = la * sfac * fast_rcp(nw);
  #pragma unroll
  for (int i = 0; i < 2; ++i) {
    size_t base = (size_t)row * N + ((size_t)t + (i << 8)) * 8;
    float4 o0, o1;
    o0.x = coef * y[i * 8 + 0]; o0.y = coef * y[i * 8 + 1];
    o0.z = coef * y[i * 8 + 2]; o0.w = coef * y[i * 8 + 3];
    o1.x = coef * y[i * 8 + 4]; o1.y = coef * y[i * 8 + 5];
    o1.z = coef * y[i * 8 + 6]; o1.w = coef * y[i * 8 + 7];
    *(float4*)(out + base) = o0;
    *(float4*)(out + base + 4) = o1;
  }
}

extern "C" void kernel_launch(void* const* d_in, const int* in_sizes, int n_in,
                              void* d_out, int out_size, void* d_ws, size_t ws_size,
                              hipStream_t stream) {
  const float* x    = (const float*)d_in[0];
  const float* z    = (const float*)d_in[1];
  const float* bias = (const float*)d_in[2];
  float* out = (float*)d_out;

  int N = in_sizes[2];           // DOUT = 4096
  int K = in_sizes[1] / N;       // DIN  = 4096
  int M = in_sizes[0] / K;       // B    = 8192

  char* ws = (char*)d_ws;
  size_t o = 0;
  __hip_bfloat16* h  = (__hip_bfloat16*)(ws + o); o += (size_t)M * K * 2;
  __hip_bfloat16* zt = (__hip_bfloat16*)(ws + o); o += (size_t)N * K * 2;
  float* cx2    = (float*)(ws + o); o += (size_t)M * 4;
  float* invomc = (float*)(ws + o); o += (size_t)M * 4;
  float* part   = (float*)(ws + o); o += (size_t)32 * N * 4;
  float* zn2    = (float*)(ws + o); o += (size_t)N * 4;
  float* invzn  = (float*)(ws + o); o += (size_t)N * 4;
  float* chb    = (float*)(ws + o); o += (size_t)N * 4;
  float* shb    = (float*)(ws + o); o += (size_t)N * 4;
  // bf16 dot intermediate — only if ws has room (verified: R15 ran this branch)
  size_t yBytes = (size_t)M * N * 2;
  bool fuse = (ws_size >= o + yBytes);
  unsigned short* ybf = (unsigned short*)(ws + o);

  const int NCH = 32;
  k_expmap<<<M, 256, 0, stream>>>(x, h, cx2, invomc, K);
  k_colsq<<<dim3(N / 1024, NCH), 256, 0, stream>>>(z, part, K, N, K / NCH);
  k_colfin<<<N / 256, 256, 0, stream>>>(part, bias, zn2, invzn, chb, shb, N, NCH);
  k_zunitT<<<dim3(N / 32, K / 32), dim3(32, 8), 0, stream>>>(z, invzn, zt, K, N);
  int grid = (M / 256) * (N / 256);
  if (fuse) {
    k_gemm_dot<1><<<grid, 512, 0, stream>>>(h, zt, out, ybf, M, N, K);
    k_mlr_bf16<<<M, 256, 0, stream>>>(ybf, out, cx2, invomc, zn2, chb, shb, N);
  } else {
    k_gemm_dot<0><<<grid, 512, 0, stream>>>(h, zt, out, ybf, M, N, K);
    k_mlr_final<<<M, 256, 0, stream>>>(out, cx2, invomc, zn2, chb, shb, N);
  }
}